// Round 4
// baseline (149.758 us; speedup 1.0000x reference)
//
#include <hip/hip_runtime.h>
#include <hip/hip_bf16.h>

// RBF-KAN as one fused bf16 MFMA GEMM:
//   out[b,o] = sum_k A[b,k] * W[k,o] + bias[o]
//   k = ic*832 + slot*64 + ii, i = ic*64+ii
//   slot==0: A = x[b,i],            W = base_w[o,i]
//   slot>=1: A = basis(x[b,i],g),   W = coeff[i,o,g],  g = slot-1
// basis(x,g) = exp(-0.5*((x-c_g)/h)^2), c_g = -4 + g*h, h = 8/11
// u = (x+4)/h = x*1.375 + 5.5 (exact):
//   basis_0 = exp(-u^2/2); basis_{g+1} = basis_g * f_g; f_0 = exp(u-0.5); f_{g+1} = f_g*e^-1
//
// Round 4: counted-vmcnt pipeline (T3+T4): B prefetch 2 steps ahead into a
// 3-deep LDS ring, raw s_barrier + s_waitcnt vmcnt(4|8) (never 0 in loop),
// setprio around MFMA cluster (T5). x-chunk prefetch issued BEFORE B-loads
// so the in-order vmcnt window count stays exact.

#define M_DIM 16384
#define N_DIM 512
#define I_DIM 512
#define KTOT  6656      // 104 K-steps of 64
#define NSTEP 104

typedef short short8 __attribute__((ext_vector_type(8)));
typedef float f32x16 __attribute__((ext_vector_type(16)));
typedef unsigned int u32x4 __attribute__((ext_vector_type(4)));

#define CVTPK(dst, lo, hi) \
  asm("v_cvt_pk_bf16_f32 %0, %1, %2" : "=v"(dst) : "v"(lo), "v"(hi))

__device__ __forceinline__ unsigned short f2bf(float f) {
  union { float f; unsigned int u; } c; c.f = f;
  unsigned int r = (c.u + 0x7FFFu + ((c.u >> 16) & 1)) >> 16;  // RNE, finite only
  return (unsigned short)r;
}

// ---------------- prep: repack coeff + base_w into bf16 Wb2[g][o][e] ----------------
// g = k >> 3 (16B k-granule, 0..831), e = k & 7.
__global__ __launch_bounds__(256) void prep_w(const float* __restrict__ coeff,
                                              const float* __restrict__ base_w,
                                              unsigned short* __restrict__ Wb2) {
  int t = blockIdx.x * 256 + threadIdx.x;   // 851968 threads, 4 shorts each
  int e0 = (t & 1) * 4;
  int go = t >> 1;                          // g*512 + o
  int o  = go & 511;
  int g  = go >> 9;
  int k4 = g * 8 + e0;
  int ic = k4 / 832;
  int rem = k4 - ic * 832;
  int slot = rem >> 6;
  int ii = rem & 63;
  int i = ic * 64 + ii;
  float v0, v1, v2, v3;
  if (slot == 0) {
    const float4 bw = *(const float4*)(base_w + (size_t)o * I_DIM + i);
    v0 = bw.x; v1 = bw.y; v2 = bw.z; v3 = bw.w;
  } else {
    int gg = slot - 1;
    const float* cp = coeff + (size_t)i * (N_DIM * 12) + o * 12 + gg;
    v0 = cp[0]; v1 = cp[6144]; v2 = cp[2 * 6144]; v3 = cp[3 * 6144];
  }
  ushort4 s;
  s.x = f2bf(v0); s.y = f2bf(v1); s.z = f2bf(v2); s.w = f2bf(v3);
  *(ushort4*)(Wb2 + (size_t)go * 8 + e0) = s;
}

// ---------------- main fused GEMM ----------------
__global__ __launch_bounds__(512, 2) void kan_gemm(const float* __restrict__ x,
                                                   const unsigned short* __restrict__ Wb2,
                                                   const float* __restrict__ bias,
                                                   float* __restrict__ out) {
  // k-granule-blocked: A [kg(8)][row(128)][8 bf16] x2, B [kg(8)][col(256)][8 bf16] x3
  __shared__ unsigned short Asw[2][8 * 128 * 8];   // 32 KB
  __shared__ unsigned short Bsw[3][8 * 256 * 8];   // 96 KB

  const int tid  = threadIdx.x;
  const int lane = tid & 63;
  const int wid  = tid >> 6;
  const int wm   = wid >> 2, wn = wid & 3;      // 2 x 4 waves, 64x64 tiles

  const int rb = blockIdx.x >> 1;
  const int cb = blockIdx.x & 1;
  const int M0 = rb * 128;
  const int N0 = cb * 256;

  // ---- A staging map: thread -> (row, 16-i chunk kgp), 16 elems each ----
  const int arow = tid & 127;
  const int kgp  = tid >> 7;                    // 0..3 -> granules 2*kgp, 2*kgp+1
  const float* xg = x + (size_t)(M0 + arow) * I_DIM + kgp * 16;
  const int aoff0 = ((kgp * 2) * 128 + arow) * 16;      // byte offsets
  const int aoff1 = ((kgp * 2 + 1) * 128 + arow) * 16;

  // ---- B staging: wave w loads granule w, cols q*64..q*64+63 (contiguous 1KB) ----
  const unsigned short* bsrc[4];
  int bdst[4];
#pragma unroll
  for (int q = 0; q < 4; ++q) {
    bsrc[q] = Wb2 + ((size_t)wid * 512 + N0 + q * 64 + lane) * 8;  // + ks*32768
    bdst[q] = (wid * 256 + q * 64) * 16;                            // byte offset
  }

  // ---- compute-side byte offsets ----
  const int l31 = lane & 31;
  const int aBase = ((lane >> 5) * 128 + wm * 64 + l31) * 16;
  const int bBase = ((lane >> 5) * 256 + wn * 64 + l31) * 16;

  f32x16 acc[2][2];
#pragma unroll
  for (int i = 0; i < 2; ++i)
#pragma unroll
    for (int j = 0; j < 2; ++j)
#pragma unroll
      for (int r = 0; r < 16; ++r) acc[i][j][r] = 0.f;

  // ---- A-gen state ----
  float4 xq[4];
#pragma unroll
  for (int q = 0; q < 4; ++q) xq[q] = *(const float4*)(xg + q * 4);  // chunk 0
  float bb[16], ff[16];
  int gic = 0;

  // ================= prologue =================
  // consume chunk 0 for slot 0, reload chunk 1 (x loads BEFORE B loads)
  float f0[16];
#pragma unroll
  for (int q = 0; q < 4; ++q) {
    f0[q*4+0] = xq[q].x; f0[q*4+1] = xq[q].y; f0[q*4+2] = xq[q].z; f0[q*4+3] = xq[q].w;
  }
#pragma unroll
  for (int q = 0; q < 4; ++q) xq[q] = *(const float4*)(xg + 64 + q * 4);  // chunk 1
  gic = 1;
  // B[0] -> ring 0, B[1] -> ring 1
#pragma unroll
  for (int q = 0; q < 4; ++q)
    __builtin_amdgcn_global_load_lds(
        (const __attribute__((address_space(1))) void*)(bsrc[q]),
        (__attribute__((address_space(3))) void*)((char*)&Bsw[0][0] + bdst[q]), 16, 0, 0);
#pragma unroll
  for (int q = 0; q < 4; ++q)
    __builtin_amdgcn_global_load_lds(
        (const __attribute__((address_space(1))) void*)(bsrc[q] + 32768),
        (__attribute__((address_space(3))) void*)((char*)&Bsw[1][0] + bdst[q]), 16, 0, 0);
  // emit A slot 0 -> Asw[0], init recurrences
  {
    unsigned int w[8];
#pragma unroll
    for (int j = 0; j < 8; ++j) CVTPK(w[j], f0[2*j], f0[2*j+1]);
    char* pA = (char*)&Asw[0][0];
    *(u32x4*)(pA + aoff0) = (u32x4){w[0], w[1], w[2], w[3]};
    *(u32x4*)(pA + aoff1) = (u32x4){w[4], w[5], w[6], w[7]};
#pragma unroll
    for (int j = 0; j < 16; ++j) {
      float u = fmaf(f0[j], 1.375f, 5.5f);
      bb[j] = exp2f(-0.72134752044448170f * u * u);                         // exp(-u^2/2)
      ff[j] = exp2f(fmaf(u, 1.44269504088896340f, -0.72134752044448170f)); // exp(u-1/2)
    }
  }
  __builtin_amdgcn_sched_barrier(0);
  asm volatile("s_waitcnt vmcnt(4) lgkmcnt(0)" ::: "memory");  // B[0] landed (x_c1+B[1] fly)
  __builtin_amdgcn_sched_barrier(0);
  __builtin_amdgcn_s_barrier();
  __builtin_amdgcn_sched_barrier(0);

  // ================= main loop =================
  int nslot = 1;        // slot generated by emitA(t+1)
  int cur3  = 0;        // B ring index for step t
  for (int t = 0; t < NSTEP; ++t) {
    const bool emit = (t < NSTEP - 1);
    const bool s0   = (nslot == 0);
    bool reload = false;
    float f[16];

    // consume x + reload next chunk (x loads FIRST -> stay oldest in vmcnt window)
    if (emit && s0) {
#pragma unroll
      for (int q = 0; q < 4; ++q) {
        f[q*4+0] = xq[q].x; f[q*4+1] = xq[q].y; f[q*4+2] = xq[q].z; f[q*4+3] = xq[q].w;
      }
      if (gic < 7) {
        const float* xn = xg + (size_t)(gic + 1) * 64;
#pragma unroll
        for (int q = 0; q < 4; ++q) xq[q] = *(const float4*)(xn + q * 4);
        reload = true;
      }
      ++gic;
    }

    // B prefetch 2 ahead
    if (t < NSTEP - 2) {
      const int nx3 = (cur3 >= 1) ? cur3 - 1 : 2;   // (t+2)%3
      char* bb2 = (char*)&Bsw[nx3][0];
      const size_t ko = (size_t)(t + 2) * 32768;
#pragma unroll
      for (int q = 0; q < 4; ++q)
        __builtin_amdgcn_global_load_lds(
            (const __attribute__((address_space(1))) void*)(bsrc[q] + ko),
            (__attribute__((address_space(3))) void*)(bb2 + bdst[q]), 16, 0, 0);
    }

    // emit A for t+1
    if (emit) {
      char* pA = (char*)&Asw[(t + 1) & 1][0];
      unsigned int w[8];
      if (s0) {
#pragma unroll
        for (int j = 0; j < 8; ++j) CVTPK(w[j], f[2*j], f[2*j+1]);
        *(u32x4*)(pA + aoff0) = (u32x4){w[0], w[1], w[2], w[3]};
        *(u32x4*)(pA + aoff1) = (u32x4){w[4], w[5], w[6], w[7]};
#pragma unroll
        for (int j = 0; j < 16; ++j) {
          float u = fmaf(f[j], 1.375f, 5.5f);
          bb[j] = exp2f(-0.72134752044448170f * u * u);
          ff[j] = exp2f(fmaf(u, 1.44269504088896340f, -0.72134752044448170f));
        }
      } else {
#pragma unroll
        for (int j = 0; j < 8; ++j) CVTPK(w[j], bb[2*j], bb[2*j+1]);
        *(u32x4*)(pA + aoff0) = (u32x4){w[0], w[1], w[2], w[3]};
        *(u32x4*)(pA + aoff1) = (u32x4){w[4], w[5], w[6], w[7]};
#pragma unroll
        for (int j = 0; j < 16; ++j) {
          bb[j] *= ff[j];
          ff[j] *= 0.36787944117144233f;          // e^-1
        }
      }
    }

    // compute step t from Asw[t&1], Bsw[cur3]
    {
      const char* pA = (const char*)&Asw[t & 1][0];
      const char* pB = (const char*)&Bsw[cur3][0];
      __builtin_amdgcn_s_setprio(1);
#pragma unroll
      for (int s = 0; s < 4; ++s) {
        const char* a = pA + aBase + s * 4096;
        const char* b = pB + bBase + s * 8192;
        short8 a0 = *(const short8*)(a);
        short8 a1 = *(const short8*)(a + 512);
        short8 b0 = *(const short8*)(b);
        short8 b1 = *(const short8*)(b + 512);
        acc[0][0] = __builtin_amdgcn_mfma_f32_32x32x16_bf16(a0, b0, acc[0][0], 0, 0, 0);
        acc[0][1] = __builtin_amdgcn_mfma_f32_32x32x16_bf16(a0, b1, acc[0][1], 0, 0, 0);
        acc[1][0] = __builtin_amdgcn_mfma_f32_32x32x16_bf16(a1, b0, acc[1][0], 0, 0, 0);
        acc[1][1] = __builtin_amdgcn_mfma_f32_32x32x16_bf16(a1, b1, acc[1][1], 0, 0, 0);
      }
      __builtin_amdgcn_s_setprio(0);
    }

    // fence: B[t+1] must land; B[t+2] (+x this step) stay in flight
    __builtin_amdgcn_sched_barrier(0);
    if (reload) {
      asm volatile("s_waitcnt vmcnt(8) lgkmcnt(0)" ::: "memory");
    } else {
      asm volatile("s_waitcnt vmcnt(4) lgkmcnt(0)" ::: "memory");
    }
    __builtin_amdgcn_sched_barrier(0);
    __builtin_amdgcn_s_barrier();
    __builtin_amdgcn_sched_barrier(0);

    nslot = (nslot == 12) ? 0 : nslot + 1;
    cur3  = (cur3 == 2) ? 0 : cur3 + 1;
  }

  // ---- epilogue: C/D 32x32 layout: col=lane&31, row=(r&3)+8*(r>>2)+4*(lane>>5) ----
  float bv[2];
#pragma unroll
  for (int fn = 0; fn < 2; ++fn) bv[fn] = bias[N0 + wn * 64 + fn * 32 + l31];
  const int rbase = (lane >> 5) * 4;
#pragma unroll
  for (int fm = 0; fm < 2; ++fm) {
#pragma unroll
    for (int fn = 0; fn < 2; ++fn) {
      const size_t cix = (size_t)(N0 + wn * 64 + fn * 32 + l31);
#pragma unroll
      for (int r = 0; r < 16; ++r) {
        int row = M0 + wm * 64 + fm * 32 + (r & 3) + 8 * (r >> 2) + rbase;
        out[(size_t)row * N_DIM + cix] = acc[fm][fn][r] + bv[fn];
      }
    }
  }
}

extern "C" void kernel_launch(void* const* d_in, const int* in_sizes, int n_in,
                              void* d_out, int out_size, void* d_ws, size_t ws_size,
                              hipStream_t stream) {
  const float* x      = (const float*)d_in[0];
  const float* coeff  = (const float*)d_in[1];
  const float* base_w = (const float*)d_in[2];
  const float* base_b = (const float*)d_in[3];
  // d_in[4] (centers) is implied by u = x*1.375 + 5.5 (exact)
  unsigned short* Wb2 = (unsigned short*)d_ws;   // needs 6,815,744 B

  prep_w<<<3328, 256, 0, stream>>>(coeff, base_w, Wb2);
  kan_gemm<<<256, 512, 0, stream>>>(x, Wb2, base_b, (float*)d_out);
}